// Round 8
// baseline (434.955 us; speedup 1.0000x reference)
//
#include <hip/hip_runtime.h>
#include <hip/hip_bf16.h>
#include <math.h>

#define L 32768
#define C 256
#define QD 512
#define SCALE (1.0f/16.0f)

typedef __hip_bfloat16 bf16;
typedef short v8s __attribute__((ext_vector_type(8)));
typedef short v4s __attribute__((ext_vector_type(4)));
typedef float v4f __attribute__((ext_vector_type(4)));
typedef float v16f __attribute__((ext_vector_type(16)));
typedef int   v4i __attribute__((ext_vector_type(4)));

__device__ __forceinline__ void ldst16(void* lds, const void* g) {
    __builtin_amdgcn_global_load_lds(
        (const __attribute__((address_space(1))) unsigned int*)g,
        (__attribute__((address_space(3))) unsigned int*)lds, 16, 0, 0);
}
__device__ __forceinline__ short bfbits(float x) {
    bf16 h = __float2bfloat16(x);
    return *reinterpret_cast<short*>(&h);
}
__device__ __forceinline__ int cvtpk(float lo, float hi) {
    int d;
    asm("v_cvt_pk_bf16_f32 %0, %1, %2" : "=v"(d) : "v"(lo), "v"(hi));
    return d;
}
// exchanges hi-32-lanes of x with lo-32-lanes of y
__device__ __forceinline__ void pl32swap(int &x, int &y) {
    asm("v_permlane32_swap_b32 %0, %1" : "+v"(x), "+v"(y));
}

// ---------------------------------------------------------------------------
// prep: pack Wq/Wk/Wv -> Wall bf16 [768][512] (Wq pre-scaled by 1/16);
// Wo -> Wob bf16 [512][256]; biases -> ball fp32 [768] (bq pre-scaled).
// ---------------------------------------------------------------------------
__global__ __launch_bounds__(256) void prep(
    const float* __restrict__ Wq, const float* __restrict__ Wk,
    const float* __restrict__ Wv, const float* __restrict__ bq,
    const float* __restrict__ bk, const float* __restrict__ bv,
    const float* __restrict__ Wo,
    bf16* __restrict__ Wall, bf16* __restrict__ Wob, float* __restrict__ ball)
{
    int i = blockIdx.x * 256 + threadIdx.x;
    if (i < 768*512) {
        int row = i >> 9, idx = i & 511;
        const float* src = row < 256 ? Wq : row < 512 ? Wk : Wv;
        float v = src[(row & 255) * 512 + idx];
        if (row < 256) v *= SCALE;
        Wall[i] = __float2bfloat16(v);
    } else if (i < 768*512 + 512*256) {
        int j = i - 768*512;
        Wob[j] = __float2bfloat16(Wo[j]);
    } else if (i < 768*512 + 512*256 + 768) {
        int j = i - 768*512 - 512*256;
        ball[j] = j < 256 ? bq[j]*SCALE : j < 512 ? bk[j - 256] : bv[j - 512];
    }
}

// ---------------------------------------------------------------------------
// convt: x1 fp32 [512][L] -> x1T bf16 [L][512], 64x64 tiles via LDS.
// ---------------------------------------------------------------------------
__global__ __launch_bounds__(256) void convt(
    const float* __restrict__ x, short* __restrict__ xT)
{
    __shared__ short st[64*72];
    const int t = threadIdx.x;
    const int l0 = blockIdx.x * 64, c0 = blockIdx.y * 64;
    #pragma unroll
    for (int i = 0; i < 2; i++) {
        int v = i*256 + t;
        int c = v >> 3, l8 = (v & 7) << 3;
        const float* p = x + (size_t)(c0 + c) * L + l0 + l8;
        float4 f0 = *(const float4*)p;
        float4 f1 = *(const float4*)(p + 4);
        bf16* stb = (bf16*)st;
        stb[(l8+0)*72 + c] = __float2bfloat16(f0.x);
        stb[(l8+1)*72 + c] = __float2bfloat16(f0.y);
        stb[(l8+2)*72 + c] = __float2bfloat16(f0.z);
        stb[(l8+3)*72 + c] = __float2bfloat16(f0.w);
        stb[(l8+4)*72 + c] = __float2bfloat16(f1.x);
        stb[(l8+5)*72 + c] = __float2bfloat16(f1.y);
        stb[(l8+6)*72 + c] = __float2bfloat16(f1.z);
        stb[(l8+7)*72 + c] = __float2bfloat16(f1.w);
    }
    __syncthreads();
    #pragma unroll
    for (int i = 0; i < 2; i++) {
        int v = i*256 + t;
        int l = v >> 3, c8 = (v & 7) << 3;
        *(v8s*)(xT + (size_t)(l0 + l) * QD + c0 + c8) = *(const v8s*)&st[l*72 + c8];
    }
}

// ---------------------------------------------------------------------------
// Fused QKV GEMM (m97-style): Y[768][L] = Wall[768][512] . x1T[L][512]^T.
// ---------------------------------------------------------------------------
__global__ __launch_bounds__(256) void qkv_gemm(
    const bf16* __restrict__ A, const bf16* __restrict__ B,
    const float* __restrict__ ball,
    bf16* __restrict__ qT, bf16* __restrict__ kT, bf16* __restrict__ vB)
{
    __shared__ short sA[128*32];
    __shared__ short sB[128*32];
    __shared__ short sE[128*136];

    const int t    = threadIdx.x;
    const int lane = t & 63;
    const int w    = t >> 6;
    const int wm   = w & 1, wn = w >> 1;
    const int col  = lane & 15, quad = lane >> 4;
    const int n0   = blockIdx.x * 128;
    const int my   = blockIdx.y;
    const int m0   = my * 128;

    v4f acc[4][4];
    #pragma unroll
    for (int i = 0; i < 4; i++)
        #pragma unroll
        for (int j = 0; j < 4; j++) acc[i][j] = (v4f){0.f,0.f,0.f,0.f};

    for (int k0 = 0; k0 < QD; k0 += 32) {
        #pragma unroll
        for (int j = 0; j < 2; j++) {
            int idx = j*256 + t;
            int m = idx >> 2, k8 = (idx & 3) << 3;
            ldst16(&sA[idx*8], A + (size_t)(m0 + m) * QD + k0 + k8);
        }
        #pragma unroll
        for (int j = 0; j < 2; j++) {
            int idx = j*256 + t;
            int n = idx >> 2, k8 = (idx & 3) << 3;
            ldst16(&sB[idx*8], B + (size_t)(n0 + n) * QD + k0 + k8);
        }
        __syncthreads();
        v8s af[4], bf[4];
        #pragma unroll
        for (int mt = 0; mt < 4; mt++)
            af[mt] = *(const v8s*)&sA[(wm*64 + mt*16 + col)*32 + quad*8];
        #pragma unroll
        for (int nt = 0; nt < 4; nt++)
            bf[nt] = *(const v8s*)&sB[(wn*64 + nt*16 + col)*32 + quad*8];
        #pragma unroll
        for (int mt = 0; mt < 4; mt++)
            #pragma unroll
            for (int nt = 0; nt < 4; nt++)
                acc[mt][nt] = __builtin_amdgcn_mfma_f32_16x16x32_bf16(af[mt], bf[nt], acc[mt][nt], 0, 0, 0);
        __syncthreads();
    }

    float bias_v[4][4];
    #pragma unroll
    for (int mt = 0; mt < 4; mt++)
        #pragma unroll
        for (int r = 0; r < 4; r++)
            bias_v[mt][r] = ball[m0 + wm*64 + mt*16 + quad*4 + r];

    bf16* sEb = (bf16*)sE;
    if (my < 4) {
        #pragma unroll
        for (int mt = 0; mt < 4; mt++)
            #pragma unroll
            for (int nt = 0; nt < 4; nt++)
                #pragma unroll
                for (int r = 0; r < 4; r++)
                    sEb[(wn*64 + nt*16 + col)*136 + wm*64 + mt*16 + quad*4 + r] =
                        __float2bfloat16(acc[mt][nt][r] + bias_v[mt][r]);
        __syncthreads();
        bf16* dst = (my < 2) ? qT : kT;
        const int c0 = (my & 1) * 128;
        #pragma unroll
        for (int j = 0; j < 8; j++) {
            int idx = j*256 + t;
            int n = idx >> 4, c8 = (idx & 15) << 3;
            *(v8s*)(dst + (size_t)(n0 + n) * C + c0 + c8) = *(const v8s*)&sE[n*136 + c8];
        }
    } else {
        #pragma unroll
        for (int mt = 0; mt < 4; mt++)
            #pragma unroll
            for (int nt = 0; nt < 4; nt++)
                #pragma unroll
                for (int r = 0; r < 4; r++)
                    sEb[(wm*64 + mt*16 + quad*4 + r)*136 + wn*64 + nt*16 + col] =
                        __float2bfloat16(acc[mt][nt][r] + bias_v[mt][r]);
        __syncthreads();
        const int c0 = (my - 4) * 128;
        #pragma unroll
        for (int j = 0; j < 8; j++) {
            int idx = j*256 + t;
            int m = idx >> 4, n8 = (idx & 15) << 3;
            *(v8s*)(vB + (size_t)(c0 + m) * L + n0 + n8) = *(const v8s*)&sE[m*136 + n8];
        }
    }
}

// ---------------------------------------------------------------------------
// Output GEMM: out[512][L] = Wob[512][256].aoT[L][256]^T + bo, * mask.
// ---------------------------------------------------------------------------
__global__ __launch_bounds__(256) void out_gemm(
    const bf16* __restrict__ A, const bf16* __restrict__ B,
    const float* __restrict__ bo, const float* __restrict__ mask,
    float* __restrict__ out)
{
    __shared__ short sA[128*32];
    __shared__ short sB[128*32];
    __shared__ float sEf[64*132];

    const int t    = threadIdx.x;
    const int lane = t & 63;
    const int w    = t >> 6;
    const int wm   = w & 1, wn = w >> 1;
    const int col  = lane & 15, quad = lane >> 4;
    const int n0   = blockIdx.x * 128;
    const int m0   = blockIdx.y * 128;

    v4f acc[4][4];
    #pragma unroll
    for (int i = 0; i < 4; i++)
        #pragma unroll
        for (int j = 0; j < 4; j++) acc[i][j] = (v4f){0.f,0.f,0.f,0.f};

    for (int k0 = 0; k0 < C; k0 += 32) {
        #pragma unroll
        for (int j = 0; j < 2; j++) {
            int idx = j*256 + t;
            int m = idx >> 2, k8 = (idx & 3) << 3;
            ldst16(&sA[idx*8], A + (size_t)(m0 + m) * C + k0 + k8);
        }
        #pragma unroll
        for (int j = 0; j < 2; j++) {
            int idx = j*256 + t;
            int n = idx >> 2, k8 = (idx & 3) << 3;
            ldst16(&sB[idx*8], B + (size_t)(n0 + n) * C + k0 + k8);
        }
        __syncthreads();
        v8s af[4], bf[4];
        #pragma unroll
        for (int mt = 0; mt < 4; mt++)
            af[mt] = *(const v8s*)&sA[(wm*64 + mt*16 + col)*32 + quad*8];
        #pragma unroll
        for (int nt = 0; nt < 4; nt++)
            bf[nt] = *(const v8s*)&sB[(wn*64 + nt*16 + col)*32 + quad*8];
        #pragma unroll
        for (int mt = 0; mt < 4; mt++)
            #pragma unroll
            for (int nt = 0; nt < 4; nt++)
                acc[mt][nt] = __builtin_amdgcn_mfma_f32_16x16x32_bf16(af[mt], bf[nt], acc[mt][nt], 0, 0, 0);
        __syncthreads();
    }

    #pragma unroll
    for (int half = 0; half < 2; half++) {
        if (wm == half) {
            #pragma unroll
            for (int mt = 0; mt < 4; mt++) {
                #pragma unroll
                for (int r = 0; r < 4; r++) {
                    float bb = bo[m0 + half*64 + mt*16 + quad*4 + r];
                    #pragma unroll
                    for (int nt = 0; nt < 4; nt++)
                        sEf[(mt*16 + quad*4 + r)*132 + wn*64 + nt*16 + col] =
                            acc[mt][nt][r] + bb;
                }
            }
        }
        __syncthreads();
        #pragma unroll
        for (int j = 0; j < 8; j++) {
            int idx = j*256 + t;
            int row = idx >> 5, s4 = (idx & 31) << 2;
            float4 vv = *(const float4*)&sEf[row*132 + s4];
            float4 mk = *(const float4*)&mask[n0 + s4];
            vv.x *= mk.x; vv.y *= mk.y; vv.z *= mk.z; vv.w *= mk.w;
            *(float4*)&out[(size_t)(m0 + half*64 + row) * L + n0 + s4] = vv;
        }
        __syncthreads();
    }
}

// ---------------------------------------------------------------------------
// Flash sliding-window attention v10: D-SPLIT wave pairs.
//  r4/r6 post-mortem: 32q/wave with full-D oacc(128) + Q-in-regs(64) can't
//  fit the 256-VGPR cap (two spill attempts). Fix: 8 waves/block, 4 q-groups
//  x 32q; each q-group is a wave PAIR splitting the output D-dim: dh=0 ->
//  D[0:128), dh=1 -> D[128:256). Per wave: oacc = 4 x v16f = 64 VGPRs,
//  qf[16] = 64 VGPRs -> peak ~204, real margin under the cap.
//  QK^T + softmax duplicated within a pair (deterministic MFMA on identical
//  inputs -> bit-identical m/l/P; MFMA pipe has slack at 6-18% util).
//  All numerics byte-reused from the r4-verified kernel: 32x32 layouts,
//  cvt_pk+permlane32_swap P-pack, bitmask validity, XOR-swizzled V staging,
//  K 264-stride staging, defer-max with alpha=0 wipe of invalid chunks.
//  DS reads per CU per chunk: 384 b128 (~4.6K cyc) vs v7's ~7.7K; staging
//  bytes halved (64KB vs 128KB per CU per chunk). 1 barrier per chunk.
//  (Round 7 was an infra failure — container died pre-pytest, same signature
//   as round 5 whose identical source then ran clean in round 6. Source
//   resubmitted byte-identical to preserve attribution.)
// ---------------------------------------------------------------------------
__device__ __forceinline__ void stage_kv(
    const short* __restrict__ kT, const short* __restrict__ vB,
    int a0, int t, short* __restrict__ sK, short* __restrict__ sV)
{
    // K: 64 rows x 33 slots of 16B (slot 32 = pad). linear slot idx = row*33+s.
    #pragma unroll
    for (int i = 0; i < 5; i++) {
        int idx = i*512 + t;
        if (idx < 2112) {
            int row = idx / 33, s = idx % 33;
            int a  = min(max(a0 + row, 0), L - 1);
            int ss = min(s, 31);
            ldst16(&sK[idx*8], kT + (size_t)a * C + ss*8);
        }
    }
    // V: 256 rows x 8 slots of 16B, XOR-swizzle via pre-swizzled source.
    #pragma unroll
    for (int i = 0; i < 4; i++) {
        int idx = i*512 + t;
        int row = idx >> 3, s = idx & 7;
        int sl  = s ^ (row & 7);
        int ab  = min(max(a0 + sl*8, 0), L - 8);
        ldst16(&sV[idx*8], vB + (size_t)row * L + ab);
    }
}

__global__ __launch_bounds__(512, 1) void attn_mfma(
    const bf16* __restrict__ qT, const bf16* __restrict__ kT,
    const bf16* __restrict__ vB, const float* __restrict__ mask,
    bf16* __restrict__ aoT)
{
    __shared__ short sK [2][64*264];   // 2 x 33.0 KB
    __shared__ short sVt[2][256*64];   // 2 x 32.0 KB -> 130 KB total

    const int t    = threadIdx.x;   // 512 threads, 8 waves
    const int w    = t >> 6;        // 0..7
    const int qgrp = w >> 1;        // 0..3: q sub-tile
    const int dh   = w & 1;         // 0/1: D-half this wave owns
    const int lane = t & 63;
    const int l31  = lane & 31;
    const int hi   = lane >> 5;
    const int bx   = blockIdx.x;
    const int tile = ((bx & 7) << 5) | (bx >> 3);   // XCD-contiguous
    const int p0   = tile * 128;
    const int abase = p0 - 256;
    const int qg   = p0 + qgrp*32 + l31;   // this lane's q row (col = l31)

    const short* kTs = (const short*)kT;
    const short* vBs = (const short*)vB;
    const short* qTs = (const short*)qT;

    // stage chunk 0 first (oldest vmem ops)
    stage_kv(kTs, vBs, abase, t, sK[0], sVt[0]);

    // Q fragments (B operand): Q[qg][ks*16 + hi*8 + j], j=0..7  (64 VGPRs)
    v8s qf[16];
    {
        const short* qp = qTs + (size_t)qg * C + hi*8;
        #pragma unroll
        for (int ks = 0; ks < 16; ks++) qf[ks] = *(const v8s*)(qp + ks*16);
    }

    // validity bitmasks: bit (kt*16 + r) of mb[ch], key = a0+kt*32+4hi+8b+c,
    // r = 4b+c  (matches 32x32 C/D: row=(r&3)+8*(r>>2)+4*hi)  [verified r4]
    unsigned mb[10];
    #pragma unroll
    for (int ch = 0; ch < 10; ch++) {
        unsigned m = 0;
        int a0 = abase + ch*64;
        #pragma unroll
        for (int kt = 0; kt < 2; kt++) {
            #pragma unroll
            for (int b = 0; b < 4; b++) {
                int a4 = a0 + kt*32 + b*8 + hi*4;
                int ac = min(max(a4, 0), L - 4);
                float4 mv = *(const float4*)&mask[ac];
                float mvv[4] = {mv.x, mv.y, mv.z, mv.w};
                #pragma unroll
                for (int c = 0; c < 4; c++) {
                    int a   = a4 + c;
                    int rel = a - qg + 256;
                    bool ok = ((unsigned)rel < 512u) &&
                              ((unsigned)a < (unsigned)L) && (mvv[c] > 0.f);
                    if (ok) m |= (1u << (kt*16 + b*4 + c));
                }
            }
        }
        mb[ch] = m;
    }

    // oacc: this wave's D-half only -> 4 x v16f = 64 VGPRs
    v16f oacc[4];
    #pragma unroll
    for (int i = 0; i < 4; i++)
        #pragma unroll
        for (int j = 0; j < 16; j++) oacc[i][j] = 0.f;
    float mrow = -1e30f, lrow = 0.f;

    // per-lane V read offsets (shorts): slot = (2j+hi)^(l31&7), j=kt*2+mf
    int voff[4];
    #pragma unroll
    for (int j = 0; j < 4; j++) voff[j] = ((2*j + hi) ^ (l31 & 7)) * 8;

    __syncthreads();

    #pragma unroll
    for (int ch = 0; ch < 10; ch++) {
        const short* sKc = sK[ch & 1];
        const short* sVc = sVt[ch & 1];
        if (ch < 9)
            stage_kv(kTs, vBs, abase + (ch+1)*64, t, sK[(ch+1)&1], sVt[(ch+1)&1]);

        // ---- per-32-key subtile: QK^T -> softmax -> PV (E live = 16 regs) --
        #pragma unroll
        for (int kt = 0; kt < 2; kt++) {
            // QK^T: A = K[key32 x k16], B = Q; D[key][q], q = l31
            // duplicated across the dh pair (identical inputs -> identical e)
            const short* kb = sKc + l31*264 + hi*8 + kt*8448;
            v16f e;
            #pragma unroll
            for (int j = 0; j < 16; j++) e[j] = 0.f;
            __builtin_amdgcn_s_setprio(1);
            #pragma unroll
            for (int ks = 0; ks < 16; ks++) {
                v8s af = *(const v8s*)(kb + ks*16);
                e = __builtin_amdgcn_mfma_f32_32x32x16_bf16(af, qf[ks], e, 0, 0, 0);
            }
            __builtin_amdgcn_s_setprio(0);

            // mask + per-q max (q lane-local; hi-pair shares q)
            unsigned mbits = mb[ch] >> (kt*16);
            float cmax = -1e30f;
            #pragma unroll
            for (int r = 0; r < 16; r++) {
                bool ok = (mbits >> r) & 1;
                float x = ok ? e[r] : -1e30f;
                e[r] = x;
                cmax = fmaxf(cmax, x);
            }
            cmax = fmaxf(cmax, __shfl_xor(cmax, 32));

            // defer-max: rescale only when max grew past threshold.
            // invalid subtiles (cmax=-1e30) never trigger; first real
            // rescale's alpha=0 wipes their garbage (verified r4).
            if (cmax > mrow + 8.f) {
                float al = __expf(mrow - cmax);
                mrow = cmax;
                lrow *= al;
                #pragma unroll
                for (int i = 0; i < 4; i++)
                    #pragma unroll
                    for (int j = 0; j < 16; j++) oacc[i][j] *= al;
            }

            // P = exp(E - m), row sum
            float psum = 0.f;
            #pragma unroll
            for (int r = 0; r < 16; r++) {
                float p = __expf(e[r] - mrow);
                e[r] = p;
                psum += p;
            }
            psum += __shfl_xor(psum, 32);
            lrow += psum;

            // pack P -> B-fragments via cvt_pk + permlane32_swap [verified r4]
            v8s pfr[2];
            #pragma unroll
            for (int g = 0; g < 2; g++) {
                int X = cvtpk(e[8*g+0], e[8*g+1]);
                int Y = cvtpk(e[8*g+2], e[8*g+3]);
                int U = cvtpk(e[8*g+4], e[8*g+5]);
                int V = cvtpk(e[8*g+6], e[8*g+7]);
                pl32swap(X, U);
                pl32swap(Y, V);
                v4i d = (v4i){X, Y, U, V};
                pfr[g] = *reinterpret_cast<v8s*>(&d);
            }

            // PV over this wave's D-half: global cht = dh*4 + cl
            const short* vb = sVc + l31*64 + dh*4*2048;
            __builtin_amdgcn_s_setprio(1);
            #pragma unroll
            for (int cl = 0; cl < 4; cl++) {
                #pragma unroll
                for (int mf = 0; mf < 2; mf++) {
                    v8s vf = *(const v8s*)(vb + cl*2048 + voff[kt*2 + mf]);
                    oacc[cl] = __builtin_amdgcn_mfma_f32_32x32x16_bf16(
                        vf, pfr[mf], oacc[cl], 0, 0, 0);
                }
            }
            __builtin_amdgcn_s_setprio(0);
        }

        if (ch < 9) __syncthreads();
    }

    // ---- epilogue: lane-local normalize + ReLU; ch = (dh*4+cl)*32+8b+4hi+c
    float inv = (lrow > 0.f) ? 1.f / lrow : 0.f;
    short* aorow = (short*)aoT + (size_t)qg * C;
    #pragma unroll
    for (int cl = 0; cl < 4; cl++) {
        #pragma unroll
        for (int b = 0; b < 4; b++) {
            v4s pk;
            #pragma unroll
            for (int c = 0; c < 4; c++)
                pk[c] = bfbits(fmaxf(oacc[cl][b*4 + c] * inv, 0.f));
            *(v4s*)(aorow + (dh*4 + cl)*32 + b*8 + hi*4) = pk;
        }
    }
}

extern "C" void kernel_launch(void* const* d_in, const int* in_sizes, int n_in,
                              void* d_out, int out_size, void* d_ws, size_t ws_size,
                              hipStream_t stream)
{
    const float* x1   = (const float*)d_in[0];
    const float* mask = (const float*)d_in[2];
    const float* Wq   = (const float*)d_in[3];
    const float* bq   = (const float*)d_in[4];
    const float* Wk   = (const float*)d_in[5];
    const float* bk   = (const float*)d_in[6];
    const float* Wv   = (const float*)d_in[7];
    const float* bv   = (const float*)d_in[8];
    const float* Wo   = (const float*)d_in[9];
    const float* bo   = (const float*)d_in[10];
    float* out = (float*)d_out;

    bf16* x1T  = (bf16*)d_ws;
    bf16* Wall = x1T + (size_t)L * QD;
    bf16* Wob  = Wall + 768*512;
    float* ball = (float*)(Wob + 512*256);
    bf16* qT   = (bf16*)(ball + 768);
    bf16* kT   = qT + (size_t)L * C;
    bf16* vB   = kT + (size_t)L * C;
    bf16* aoT  = vB + (size_t)L * C;

    dim3 blk(256);
    prep<<<dim3((768*512 + 512*256 + 768 + 255)/256), blk, 0, stream>>>(
        Wq, Wk, Wv, bq, bk, bv, Wo, Wall, Wob, ball);
    convt<<<dim3(L/64, QD/64), blk, 0, stream>>>(x1, (short*)x1T);
    qkv_gemm<<<dim3(L/128, 6), blk, 0, stream>>>(Wall, x1T, ball, qT, kT, vB);
    attn_mfma<<<dim3(L/128), dim3(512), 0, stream>>>(qT, kT, vB, mask, aoT);
    out_gemm<<<dim3(L/128, 4), blk, 0, stream>>>(Wob, aoT, bo, mask, out);
}

// Round 9
// 310.612 us; speedup vs baseline: 1.4003x; 1.4003x over previous
//
#include <hip/hip_runtime.h>
#include <hip/hip_bf16.h>
#include <math.h>

#define L 32768
#define C 256
#define QD 512
#define SCALE (1.0f/16.0f)

typedef __hip_bfloat16 bf16;
typedef short v8s __attribute__((ext_vector_type(8)));
typedef short v4s __attribute__((ext_vector_type(4)));
typedef float v4f __attribute__((ext_vector_type(4)));

__device__ __forceinline__ void ldst16(void* lds, const void* g) {
    __builtin_amdgcn_global_load_lds(
        (const __attribute__((address_space(1))) unsigned int*)g,
        (__attribute__((address_space(3))) unsigned int*)lds, 16, 0, 0);
}
__device__ __forceinline__ short bfbits(float x) {
    bf16 h = __float2bfloat16(x);
    return *reinterpret_cast<short*>(&h);
}

// ---------------------------------------------------------------------------
// prep: pack Wq/Wk/Wv -> Wall bf16 [768][512]; Wo -> Wob bf16 [512][256];
// biases -> ball fp32 [768].  (No pre-scaling: v4 attn applies SCALE itself.)
// ---------------------------------------------------------------------------
__global__ __launch_bounds__(256) void prep(
    const float* __restrict__ Wq, const float* __restrict__ Wk,
    const float* __restrict__ Wv, const float* __restrict__ bq,
    const float* __restrict__ bk, const float* __restrict__ bv,
    const float* __restrict__ Wo,
    bf16* __restrict__ Wall, bf16* __restrict__ Wob, float* __restrict__ ball)
{
    int i = blockIdx.x * 256 + threadIdx.x;
    if (i < 768*512) {
        int row = i >> 9, idx = i & 511;
        const float* src = row < 256 ? Wq : row < 512 ? Wk : Wv;
        Wall[i] = __float2bfloat16(src[(row & 255) * 512 + idx]);
    } else if (i < 768*512 + 512*256) {
        int j = i - 768*512;
        Wob[j] = __float2bfloat16(Wo[j]);
    } else if (i < 768*512 + 512*256 + 768) {
        int j = i - 768*512 - 512*256;
        ball[j] = j < 256 ? bq[j] : j < 512 ? bk[j - 256] : bv[j - 512];
    }
}

// ---------------------------------------------------------------------------
// Fused QKV GEMM v11: Y[768][L] = Wall[768][512] . x1[512][L]  (B read
// DIRECTLY from x1 f32 — the convt pre-transpose kernel is deleted; its
// 96 MB HBM round-trip is absorbed into staging: coalesced f32 row loads ->
// cvt -> transposed bf16 LDS tile).
// sB layout: [128 n][40 k-shorts], 16B slot s stored at s^(n&3) (XOR swizzle;
// naive stride-40 would be a 16-way write conflict: 20*(n=16m) === 0 mod 32).
// Fragment reads stay ds_read_b128 at slot quad^(col&3).
// ---------------------------------------------------------------------------
__global__ __launch_bounds__(256) void qkv_gemm(
    const bf16* __restrict__ A, const float* __restrict__ X,
    const float* __restrict__ ball,
    bf16* __restrict__ qT, bf16* __restrict__ kT, bf16* __restrict__ vB)
{
    __shared__ short sA[128*32];
    __shared__ short sB[128*40];
    __shared__ short sE[128*136];

    const int t    = threadIdx.x;
    const int lane = t & 63;
    const int w    = t >> 6;
    const int wm   = w & 1, wn = w >> 1;
    const int col  = lane & 15, quad = lane >> 4;
    const int n0   = blockIdx.x * 128;
    const int my   = blockIdx.y;
    const int m0   = my * 128;

    // B-staging coords: this thread loads x1[k0+cB][n0+lB .. +15]
    const int cB = t >> 3;          // k-row within tile, 0..31
    const int lB = (t & 7) << 4;    // n-start, 0..112

    v4f acc[4][4];
    #pragma unroll
    for (int i = 0; i < 4; i++)
        #pragma unroll
        for (int j = 0; j < 4; j++) acc[i][j] = (v4f){0.f,0.f,0.f,0.f};

    for (int k0 = 0; k0 < QD; k0 += 32) {
        // ---- A staging via async gload_lds ----
        #pragma unroll
        for (int j = 0; j < 2; j++) {
            int idx = j*256 + t;
            int m = idx >> 2, k8 = (idx & 3) << 3;
            ldst16(&sA[idx*8], A + (size_t)(m0 + m) * QD + k0 + k8);
        }
        // ---- B staging: f32 row loads -> cvt -> swizzled transpose ----
        {
            const float* xp = X + (size_t)(k0 + cB) * L + n0 + lB;
            float4 f[4];
            #pragma unroll
            for (int j = 0; j < 4; j++) f[j] = *(const float4*)(xp + j*4);
            const float* fs = (const float*)f;
            #pragma unroll
            for (int i = 0; i < 16; i++) {
                int n = lB + i;
                int sl = (cB >> 3) ^ (i & 3);      // n&3 == i&3 (lB mult of 16)
                sB[n*40 + (sl << 3) + (cB & 7)] = bfbits(fs[i]);
            }
        }
        __syncthreads();
        v8s af[4], bfr[4];
        #pragma unroll
        for (int mt = 0; mt < 4; mt++)
            af[mt] = *(const v8s*)&sA[(wm*64 + mt*16 + col)*32 + quad*8];
        #pragma unroll
        for (int nt = 0; nt < 4; nt++) {
            int n = wn*64 + nt*16 + col;
            bfr[nt] = *(const v8s*)&sB[n*40 + ((quad ^ (col & 3)) << 3)];
        }
        #pragma unroll
        for (int mt = 0; mt < 4; mt++)
            #pragma unroll
            for (int nt = 0; nt < 4; nt++)
                acc[mt][nt] = __builtin_amdgcn_mfma_f32_16x16x32_bf16(af[mt], bfr[nt], acc[mt][nt], 0, 0, 0);
        __syncthreads();
    }

    float bias_v[4][4];
    #pragma unroll
    for (int mt = 0; mt < 4; mt++)
        #pragma unroll
        for (int r = 0; r < 4; r++)
            bias_v[mt][r] = ball[m0 + wm*64 + mt*16 + quad*4 + r];

    bf16* sEb = (bf16*)sE;
    if (my < 4) {
        #pragma unroll
        for (int mt = 0; mt < 4; mt++)
            #pragma unroll
            for (int nt = 0; nt < 4; nt++)
                #pragma unroll
                for (int r = 0; r < 4; r++)
                    sEb[(wn*64 + nt*16 + col)*136 + wm*64 + mt*16 + quad*4 + r] =
                        __float2bfloat16(acc[mt][nt][r] + bias_v[mt][r]);
        __syncthreads();
        bf16* dst = (my < 2) ? qT : kT;
        const int c0 = (my & 1) * 128;
        #pragma unroll
        for (int j = 0; j < 8; j++) {
            int idx = j*256 + t;
            int n = idx >> 4, c8 = (idx & 15) << 3;
            *(v8s*)(dst + (size_t)(n0 + n) * C + c0 + c8) = *(const v8s*)&sE[n*136 + c8];
        }
    } else {
        #pragma unroll
        for (int mt = 0; mt < 4; mt++)
            #pragma unroll
            for (int nt = 0; nt < 4; nt++)
                #pragma unroll
                for (int r = 0; r < 4; r++)
                    sEb[(wm*64 + mt*16 + quad*4 + r)*136 + wn*64 + nt*16 + col] =
                        __float2bfloat16(acc[mt][nt][r] + bias_v[mt][r]);
        __syncthreads();
        const int c0 = (my - 4) * 128;
        #pragma unroll
        for (int j = 0; j < 8; j++) {
            int idx = j*256 + t;
            int m = idx >> 4, n8 = (idx & 15) << 3;
            *(v8s*)(vB + (size_t)(c0 + m) * L + n0 + n8) = *(const v8s*)&sE[m*136 + n8];
        }
    }
}

// ---------------------------------------------------------------------------
// Output GEMM: out[512][L] = Wob[512][256].aoT[L][256]^T + bo, * mask.
// ---------------------------------------------------------------------------
__global__ __launch_bounds__(256) void out_gemm(
    const bf16* __restrict__ A, const bf16* __restrict__ B,
    const float* __restrict__ bo, const float* __restrict__ mask,
    float* __restrict__ out)
{
    __shared__ short sA[128*32];
    __shared__ short sB[128*32];
    __shared__ float sEf[64*132];

    const int t    = threadIdx.x;
    const int lane = t & 63;
    const int w    = t >> 6;
    const int wm   = w & 1, wn = w >> 1;
    const int col  = lane & 15, quad = lane >> 4;
    const int n0   = blockIdx.x * 128;
    const int m0   = blockIdx.y * 128;

    v4f acc[4][4];
    #pragma unroll
    for (int i = 0; i < 4; i++)
        #pragma unroll
        for (int j = 0; j < 4; j++) acc[i][j] = (v4f){0.f,0.f,0.f,0.f};

    for (int k0 = 0; k0 < C; k0 += 32) {
        #pragma unroll
        for (int j = 0; j < 2; j++) {
            int idx = j*256 + t;
            int m = idx >> 2, k8 = (idx & 3) << 3;
            ldst16(&sA[idx*8], A + (size_t)(m0 + m) * C + k0 + k8);
        }
        #pragma unroll
        for (int j = 0; j < 2; j++) {
            int idx = j*256 + t;
            int n = idx >> 2, k8 = (idx & 3) << 3;
            ldst16(&sB[idx*8], B + (size_t)(n0 + n) * C + k0 + k8);
        }
        __syncthreads();
        v8s af[4], bfr[4];
        #pragma unroll
        for (int mt = 0; mt < 4; mt++)
            af[mt] = *(const v8s*)&sA[(wm*64 + mt*16 + col)*32 + quad*8];
        #pragma unroll
        for (int nt = 0; nt < 4; nt++)
            bfr[nt] = *(const v8s*)&sB[(wn*64 + nt*16 + col)*32 + quad*8];
        #pragma unroll
        for (int mt = 0; mt < 4; mt++)
            #pragma unroll
            for (int nt = 0; nt < 4; nt++)
                acc[mt][nt] = __builtin_amdgcn_mfma_f32_16x16x32_bf16(af[mt], bfr[nt], acc[mt][nt], 0, 0, 0);
        __syncthreads();
    }

    #pragma unroll
    for (int half = 0; half < 2; half++) {
        if (wm == half) {
            #pragma unroll
            for (int mt = 0; mt < 4; mt++) {
                #pragma unroll
                for (int r = 0; r < 4; r++) {
                    float bb = bo[m0 + half*64 + mt*16 + quad*4 + r];
                    #pragma unroll
                    for (int nt = 0; nt < 4; nt++)
                        sEf[(mt*16 + quad*4 + r)*132 + wn*64 + nt*16 + col] =
                            acc[mt][nt][r] + bb;
                }
            }
        }
        __syncthreads();
        #pragma unroll
        for (int j = 0; j < 8; j++) {
            int idx = j*256 + t;
            int row = idx >> 5, s4 = (idx & 31) << 2;
            float4 vv = *(const float4*)&sEf[row*132 + s4];
            float4 mk = *(const float4*)&mask[n0 + s4];
            vv.x *= mk.x; vv.y *= mk.y; vv.z *= mk.z; vv.w *= mk.w;
            *(float4*)&out[(size_t)(m0 + half*64 + row) * L + n0 + s4] = vv;
        }
        __syncthreads();
    }
}

// ---------------------------------------------------------------------------
// Flash sliding-window attention — v4 RESTORED verbatim (round-0 baseline:
// 62-64 µs, VGPR 112, zero spill). Rounds 1-8 established: (1) the ~64 µs
// is a phase-serialization floor for this family; (2) 32q/32x32-MFMA
// variants need ~190+ arch VGPRs and spill at every reachable thread shape;
// (3) q-tile shrink (for 2 blocks/CU) inflates window work by the same
// factor it gains in overlap. v4 is the best measured point.
// ---------------------------------------------------------------------------
__device__ __forceinline__ void load_chunk(
    const short* __restrict__ kT, const short* __restrict__ vB,
    int a0, int t, v8s kreg[4], v8s vreg[4])
{
    #pragma unroll
    for (int j = 0; j < 4; j++) {
        int idx = j*512 + t;
        int r = idx >> 5, s = idx & 31;
        int a = min(max(a0 + r, 0), L - 1);
        kreg[j] = *(const v8s*)(kT + (size_t)a * C + s*8);
    }
    #pragma unroll
    for (int j = 0; j < 4; j++) {
        int idx = j*512 + t;
        int c = idx >> 3, s = idx & 7;
        int ab = min(max(a0 + s*8, 0), L - 8);
        vreg[j] = *(const v8s*)(vB + (size_t)c * L + ab);
    }
}

__device__ __forceinline__ void store_chunk(
    short* __restrict__ sK, short* __restrict__ sVt, int t,
    const v8s kreg[4], const v8s vreg[4])
{
    #pragma unroll
    for (int j = 0; j < 4; j++) {
        int idx = j*512 + t;
        int r = idx >> 5, s = idx & 31;
        *(v8s*)&sK[r*264 + s*8] = kreg[j];
    }
    #pragma unroll
    for (int j = 0; j < 4; j++) {
        int idx = j*512 + t;
        int c = idx >> 3, s = idx & 7;
        *(v8s*)&sVt[c*72 + s*8] = vreg[j];
    }
}

__global__ __launch_bounds__(512, 1) void attn_mfma(
    const bf16* __restrict__ qT, const bf16* __restrict__ kT,
    const bf16* __restrict__ vB, const float* __restrict__ mask,
    bf16* __restrict__ aoT)
{
    __shared__ short sK [2][64*264];
    __shared__ short sVt[2][256*72];
    __shared__ short sP [8][16*72];

    const int t    = threadIdx.x;
    const int w    = t >> 6;
    const int lane = t & 63;
    const int col  = lane & 15;
    const int quad = lane >> 4;
    const int bx   = blockIdx.x;
    const int tile = ((bx & 7) << 5) | (bx >> 3);
    const int p0   = tile * 128;
    const int abase = p0 - 256;

    v8s qf[8];
    {
        const short* qp = (const short*)qT + (size_t)(p0 + w*16 + col) * C + quad*8;
        #pragma unroll
        for (int ks = 0; ks < 8; ks++) qf[ks] = *(const v8s*)(qp + ks*32);
    }

    v4f oacc[16];
    #pragma unroll
    for (int i = 0; i < 16; i++) oacc[i] = (v4f){0.f, 0.f, 0.f, 0.f};
    float mrow[4] = {-1e30f, -1e30f, -1e30f, -1e30f};
    float lrow[4] = {0.f, 0.f, 0.f, 0.f};

    const short* kTs = (const short*)kT;
    const short* vBs = (const short*)vB;
    bf16* sPw  = (bf16*)sP[w];
    const short* sPws = (const short*)sP[w];

    v8s kreg[4], vreg[4];
    load_chunk(kTs, vBs, abase, t, kreg, vreg);
    store_chunk(sK[0], sVt[0], t, kreg, vreg);
    __syncthreads();

    for (int ch = 0; ch < 10; ch++) {
        const int a0  = abase + ch*64;
        const int cur = ch & 1;
        const bool pf = (ch < 9);
        if (pf)
            load_chunk(kTs, vBs, a0 + 64, t, kreg, vreg);

        v4f e[4];
        #pragma unroll
        for (int nt = 0; nt < 4; nt++) {
            v4f acc = {0.f, 0.f, 0.f, 0.f};
            const short* kp = &sK[cur][(nt*16 + col)*264 + quad*8];
            #pragma unroll
            for (int ks = 0; ks < 8; ks++) {
                v8s bfrag = *(const v8s*)(kp + ks*32);
                acc = __builtin_amdgcn_mfma_f32_16x16x32_bf16(qf[ks], bfrag, acc, 0, 0, 0);
            }
            e[nt] = acc;
        }

        float cmax[4] = {-1e30f, -1e30f, -1e30f, -1e30f};
        #pragma unroll
        for (int nt = 0; nt < 4; nt++) {
            int a  = a0 + nt*16 + col;
            int aa = ch*64 + nt*16 + col;
            float mval = (a >= 0 && a < L) ? mask[a] : 0.f;
            #pragma unroll
            for (int r = 0; r < 4; r++) {
                int rel = aa - (w*16 + quad*4 + r);
                bool valid = ((unsigned)rel < 512u) && (mval > 0.f);
                float ev = valid ? e[nt][r] * SCALE : -1e30f;
                e[nt][r] = ev;
                cmax[r] = fmaxf(cmax[r], ev);
            }
        }
        #pragma unroll
        for (int off = 1; off < 16; off <<= 1) {
            #pragma unroll
            for (int r = 0; r < 4; r++)
                cmax[r] = fmaxf(cmax[r], __shfl_xor(cmax[r], off));
        }

        float alpha[4];
        #pragma unroll
        for (int r = 0; r < 4; r++) {
            float mnew = fmaxf(mrow[r], cmax[r]);
            alpha[r] = __expf(mrow[r] - mnew);
            mrow[r] = mnew;
        }

        float psum[4] = {0.f, 0.f, 0.f, 0.f};
        #pragma unroll
        for (int nt = 0; nt < 4; nt++) {
            #pragma unroll
            for (int r = 0; r < 4; r++) {
                float ev = e[nt][r];
                float p = (ev > -9e29f) ? __expf(ev - mrow[r]) : 0.f;
                psum[r] += p;
                sPw[(quad*4 + r)*72 + nt*16 + col] = __float2bfloat16(p);
            }
        }
        #pragma unroll
        for (int off = 1; off < 16; off <<= 1) {
            #pragma unroll
            for (int r = 0; r < 4; r++)
                psum[r] += __shfl_xor(psum[r], off);
        }
        #pragma unroll
        for (int r = 0; r < 4; r++) lrow[r] = lrow[r]*alpha[r] + psum[r];

        {
            int src = (col >> 2) << 4;
            float a0b = __shfl(alpha[0], src);
            float a1b = __shfl(alpha[1], src);
            float a2b = __shfl(alpha[2], src);
            float a3b = __shfl(alpha[3], src);
            int rr = col & 3;
            float aO = (rr == 0) ? a0b : (rr == 1) ? a1b : (rr == 2) ? a2b : a3b;
            #pragma unroll
            for (int i = 0; i < 16; i++) {
                oacc[i][0] *= aO; oacc[i][1] *= aO;
                oacc[i][2] *= aO; oacc[i][3] *= aO;
            }
        }

        {
            v8s pf0 = *(const v8s*)&sPws[col*72 + quad*8];
            v8s pf1 = *(const v8s*)&sPws[col*72 + quad*8 + 32];
            #pragma unroll
            for (int ct = 0; ct < 16; ct++) {
                const short* vp = &sVt[cur][(ct*16 + col)*72 + quad*8];
                v8s vf0 = *(const v8s*)vp;
                v8s vf1 = *(const v8s*)(vp + 32);
                oacc[ct] = __builtin_amdgcn_mfma_f32_16x16x32_bf16(vf0, pf0, oacc[ct], 0, 0, 0);
                oacc[ct] = __builtin_amdgcn_mfma_f32_16x16x32_bf16(vf1, pf1, oacc[ct], 0, 0, 0);
            }
        }

        if (pf) {
            store_chunk(sK[cur ^ 1], sVt[cur ^ 1], t, kreg, vreg);
            __syncthreads();
        }
    }

    {
        int src = (col >> 2) << 4;
        float l0b = __shfl(lrow[0], src);
        float l1b = __shfl(lrow[1], src);
        float l2b = __shfl(lrow[2], src);
        float l3b = __shfl(lrow[3], src);
        int rr = col & 3;
        float lO = (rr == 0) ? l0b : (rr == 1) ? l1b : (rr == 2) ? l2b : l3b;
        float inv = (lO > 0.f) ? 1.f / lO : 0.f;
        const int qg = p0 + w*16 + col;
        short* aorow = (short*)aoT + (size_t)qg * C;
        #pragma unroll
        for (int ct = 0; ct < 16; ct++) {
            v4s pk;
            #pragma unroll
            for (int r = 0; r < 4; r++)
                pk[r] = bfbits(fmaxf(oacc[ct][r] * inv, 0.f));
            *(v4s*)(aorow + ct*16 + quad*4) = pk;
        }
    }
}

extern "C" void kernel_launch(void* const* d_in, const int* in_sizes, int n_in,
                              void* d_out, int out_size, void* d_ws, size_t ws_size,
                              hipStream_t stream)
{
    const float* x1   = (const float*)d_in[0];
    const float* mask = (const float*)d_in[2];
    const float* Wq   = (const float*)d_in[3];
    const float* bq   = (const float*)d_in[4];
    const float* Wk   = (const float*)d_in[5];
    const float* bk   = (const float*)d_in[6];
    const float* Wv   = (const float*)d_in[7];
    const float* bv   = (const float*)d_in[8];
    const float* Wo   = (const float*)d_in[9];
    const float* bo   = (const float*)d_in[10];
    float* out = (float*)d_out;

    bf16* Wall = (bf16*)d_ws;
    bf16* Wob  = Wall + 768*512;
    float* ball = (float*)(Wob + 512*256);
    bf16* qT   = (bf16*)(ball + 768);
    bf16* kT   = qT + (size_t)L * C;
    bf16* vB   = kT + (size_t)L * C;
    bf16* aoT  = vB + (size_t)L * C;

    dim3 blk(256);
    prep<<<dim3((768*512 + 512*256 + 768 + 255)/256), blk, 0, stream>>>(
        Wq, Wk, Wv, bq, bk, bv, Wo, Wall, Wob, ball);
    qkv_gemm<<<dim3(L/128, 6), blk, 0, stream>>>(Wall, x1, ball, qT, kT, vB);
    attn_mfma<<<dim3(L/128), dim3(512), 0, stream>>>(qT, kT, vB, mask, aoT);
    out_gemm<<<dim3(L/128, 4), blk, 0, stream>>>(Wob, aoT, bo, mask, out);
}